// Round 1
// baseline (1765.458 us; speedup 1.0000x reference)
//
#include <hip/hip_runtime.h>

#define B_    1024
#define N_    100000
#define NR_   500
#define D_    200
#define OC_   32
#define FW_   9
#define L_    192
#define OCL_  6144     // OC_*L_
#define EPS_  1e-5f

// ---------------- Stage A: x = bn0(E[e1]), k = bn1-scale * (R[r]@W_fc1 + b_fc1),
// y[b,o,l] = sum_w x[l+w]*k[o,w] + t1[o]  -> y_ws[b][o*L+l] ----------------
__global__ __launch_bounds__(256) void kA(
    const int* __restrict__ e1_idx, const int* __restrict__ r_idx,
    const float* __restrict__ E, const float* __restrict__ R,
    const float* __restrict__ W_fc1, const float* __restrict__ b_fc1,
    const float* __restrict__ bn0_g, const float* __restrict__ bn0_b,
    const float* __restrict__ bn0_m, const float* __restrict__ bn0_v,
    const float* __restrict__ bn1_g, const float* __restrict__ bn1_b,
    const float* __restrict__ bn1_m, const float* __restrict__ bn1_v,
    float* __restrict__ y_ws)
{
    __shared__ float x_lds[D_];
    __shared__ float r_lds[D_];
    __shared__ float k_lds[OC_ * FW_];
    __shared__ float s1_lds[OC_], t1_lds[OC_];

    const int b   = blockIdx.x;
    const int tid = threadIdx.x;

    const float s0 = bn0_g[0] / sqrtf(bn0_v[0] + EPS_);
    const float c0 = bn0_b[0] - bn0_m[0] * s0;

    if (tid < D_) {
        x_lds[tid] = E[(long)e1_idx[b] * D_ + tid] * s0 + c0;
        r_lds[tid] = R[(long)r_idx[b] * D_ + tid];
    } else if (tid >= 224) {
        int o = tid - 224;
        float s1 = bn1_g[o] / sqrtf(bn1_v[o] + EPS_);
        s1_lds[o] = s1;
        t1_lds[o] = bn1_b[o] - bn1_m[o] * s1;
    }
    __syncthreads();

    for (int j = tid; j < OC_ * FW_; j += 256) {
        float acc = b_fc1[j];
        #pragma unroll 4
        for (int d = 0; d < D_; ++d)
            acc += r_lds[d] * W_fc1[d * (OC_ * FW_) + j];
        k_lds[j] = acc * s1_lds[j / FW_];
    }
    __syncthreads();

    float* yrow = y_ws + (long)b * OCL_;
    for (int idx = tid; idx < OCL_; idx += 256) {
        int o = idx / L_;
        int l = idx - o * L_;
        const float* kp = &k_lds[o * FW_];
        float acc = t1_lds[o];
        #pragma unroll
        for (int w = 0; w < FW_; ++w)
            acc += x_lds[l + w] * kp[w];
        yrow[idx] = acc;
    }
}

// ---------------- Stage B: pre[ks][b][d] = partial( y[b,:] @ W_fc[:,d] ) ----------------
// grid: (d_tiles=4, b_tiles=16, ksplit=4); tile 64b x 64d; micro 4x4
__global__ __launch_bounds__(256) void kB(
    const float* __restrict__ y_ws, const float* __restrict__ W_fc,
    float* __restrict__ pre)
{
    __shared__ float y_lds[64][68];   // [k][b]
    __shared__ float w_lds[64][68];   // [k][d]

    const int tid = threadIdx.x;
    const int d0 = blockIdx.x * 64;
    const int b0 = blockIdx.y * 64;
    const int k0 = blockIdx.z * (OCL_ / 4);
    const int tx = tid & 15, ty = tid >> 4;

    float acc[4][4] = {};

    for (int kc = 0; kc < OCL_ / 4; kc += 64) {
        #pragma unroll
        for (int i = 0; i < 16; ++i) {
            int t = tid + i * 256;
            int hi = t >> 6, lo = t & 63;
            y_lds[lo][hi] = y_ws[(long)(b0 + hi) * OCL_ + (k0 + kc + lo)];
            w_lds[hi][lo] = (d0 + lo < D_)
                ? W_fc[(long)(k0 + kc + hi) * D_ + (d0 + lo)] : 0.f;
        }
        __syncthreads();
        #pragma unroll
        for (int kk = 0; kk < 64; ++kk) {
            float4 yv = *(const float4*)&y_lds[kk][ty * 4];
            float4 wv = *(const float4*)&w_lds[kk][tx * 4];
            float ya[4] = {yv.x, yv.y, yv.z, yv.w};
            float wa[4] = {wv.x, wv.y, wv.z, wv.w};
            #pragma unroll
            for (int i = 0; i < 4; ++i)
                #pragma unroll
                for (int j = 0; j < 4; ++j)
                    acc[i][j] += ya[i] * wa[j];
        }
        __syncthreads();
    }

    #pragma unroll
    for (int i = 0; i < 4; ++i) {
        int brow = b0 + ty * 4 + i;
        #pragma unroll
        for (int j = 0; j < 4; ++j) {
            int d = d0 + tx * 4 + j;
            if (d < D_)
                pre[((long)blockIdx.z * B_ + brow) * D_ + d] = acc[i][j];
        }
    }
}

// ---------------- Stage B2: reduce splits + bias + bn2 + relu -> h_ws ----------------
__global__ __launch_bounds__(256) void kB2(
    const float* __restrict__ pre, const float* __restrict__ b_fc,
    const float* __restrict__ bn2_g, const float* __restrict__ bn2_b,
    const float* __restrict__ bn2_m, const float* __restrict__ bn2_v,
    float* __restrict__ h_ws)
{
    int id = blockIdx.x * 256 + threadIdx.x;
    if (id >= B_ * D_) return;
    int d = id % D_;
    float s = pre[id] + pre[B_ * D_ + id] + pre[2 * B_ * D_ + id] + pre[3 * B_ * D_ + id];
    float s2 = bn2_g[d] / sqrtf(bn2_v[d] + EPS_);
    float h = (s + b_fc[d] - bn2_m[d]) * s2 + bn2_b[d];
    h_ws[id] = fmaxf(h, 0.f);
}

// ---------------- Stage C: out[b][n] = sigmoid(h[b,:] . E[n,:] + bias[n]) ----------------
// tile 64b x 128n, K chunks of 50; micro 4b x 8n
__global__ __launch_bounds__(256) void kC(
    const float* __restrict__ h_ws, const float* __restrict__ E,
    const float* __restrict__ bias, float* __restrict__ out)
{
    __shared__ float h_lds[50][68];    // [k][b]
    __shared__ float e_lds[50][132];   // [k][n]

    const int tid = threadIdx.x;
    const int n0 = blockIdx.x * 128;
    const int b0 = blockIdx.y * 64;
    const int tx = tid & 15, ty = tid >> 4;

    float acc[4][8] = {};

    for (int k0 = 0; k0 < D_; k0 += 50) {
        for (int t = tid; t < 64 * 50; t += 256) {
            int bb = t / 50, kk = t - bb * 50;
            h_lds[kk][bb] = h_ws[(long)(b0 + bb) * D_ + (k0 + kk)];
        }
        for (int t = tid; t < 128 * 50; t += 256) {
            int nn = t / 50, kk = t - nn * 50;
            int n = n0 + nn;
            e_lds[kk][nn] = (n < N_) ? E[(long)n * D_ + (k0 + kk)] : 0.f;
        }
        __syncthreads();
        #pragma unroll
        for (int kk = 0; kk < 50; ++kk) {
            float4 hv  = *(const float4*)&h_lds[kk][ty * 4];
            float4 ev0 = *(const float4*)&e_lds[kk][tx * 8];
            float4 ev1 = *(const float4*)&e_lds[kk][tx * 8 + 4];
            float ha[4] = {hv.x, hv.y, hv.z, hv.w};
            float ea[8] = {ev0.x, ev0.y, ev0.z, ev0.w, ev1.x, ev1.y, ev1.z, ev1.w};
            #pragma unroll
            for (int i = 0; i < 4; ++i)
                #pragma unroll
                for (int j = 0; j < 8; ++j)
                    acc[i][j] += ha[i] * ea[j];
        }
        __syncthreads();
    }

    int n = n0 + tx * 8;
    if (n < N_) {   // N_ % 8 == 0, so all 8 are valid together
        float4 bv0 = *(const float4*)&bias[n];
        float4 bv1 = *(const float4*)&bias[n + 4];
        float ba[8] = {bv0.x, bv0.y, bv0.z, bv0.w, bv1.x, bv1.y, bv1.z, bv1.w};
        #pragma unroll
        for (int i = 0; i < 4; ++i) {
            long base = (long)(b0 + ty * 4 + i) * N_ + n;
            float4 o0, o1;
            float* o0p = &o0.x; float* o1p = &o1.x;
            #pragma unroll
            for (int j = 0; j < 4; ++j) {
                float v = acc[i][j] + ba[j];
                o0p[j] = 1.f / (1.f + __expf(-v));
            }
            #pragma unroll
            for (int j = 0; j < 4; ++j) {
                float v = acc[i][j + 4] + ba[j + 4];
                o1p[j] = 1.f / (1.f + __expf(-v));
            }
            *(float4*)&out[base]     = o0;
            *(float4*)&out[base + 4] = o1;
        }
    }
}

extern "C" void kernel_launch(void* const* d_in, const int* in_sizes, int n_in,
                              void* d_out, int out_size, void* d_ws, size_t ws_size,
                              hipStream_t stream) {
    const int*   e1_idx = (const int*)d_in[0];
    const int*   r_idx  = (const int*)d_in[1];
    const float* E      = (const float*)d_in[2];
    const float* R      = (const float*)d_in[3];
    const float* W_fc   = (const float*)d_in[4];
    const float* b_fc   = (const float*)d_in[5];
    const float* W_fc1  = (const float*)d_in[6];
    const float* b_fc1  = (const float*)d_in[7];
    const float* bn0_g  = (const float*)d_in[8];
    const float* bn0_b  = (const float*)d_in[9];
    const float* bn0_m  = (const float*)d_in[10];
    const float* bn0_v  = (const float*)d_in[11];
    const float* bn1_g  = (const float*)d_in[12];
    const float* bn1_b  = (const float*)d_in[13];
    const float* bn1_m  = (const float*)d_in[14];
    const float* bn1_v  = (const float*)d_in[15];
    const float* bn2_g  = (const float*)d_in[16];
    const float* bn2_b  = (const float*)d_in[17];
    const float* bn2_m  = (const float*)d_in[18];
    const float* bn2_v  = (const float*)d_in[19];
    const float* bias   = (const float*)d_in[20];
    float* out = (float*)d_out;

    float* y_ws = (float*)d_ws;                 // B*OCL = 6,291,456 floats
    float* pre  = y_ws + (long)B_ * OCL_;       // 4*B*D = 819,200 floats
    float* h_ws = pre + 4L * B_ * D_;           // B*D   = 204,800 floats

    kA<<<B_, 256, 0, stream>>>(e1_idx, r_idx, E, R, W_fc1, b_fc1,
                               bn0_g, bn0_b, bn0_m, bn0_v,
                               bn1_g, bn1_b, bn1_m, bn1_v, y_ws);
    kB<<<dim3(4, 16, 4), 256, 0, stream>>>(y_ws, W_fc, pre);
    kB2<<<(B_ * D_ + 255) / 256, 256, 0, stream>>>(pre, b_fc, bn2_g, bn2_b, bn2_m, bn2_v, h_ws);
    kC<<<dim3((N_ + 127) / 128, B_ / 64), 256, 0, stream>>>(h_ws, E, bias, out);
}

// Round 2
// 821.402 us; speedup vs baseline: 2.1493x; 2.1493x over previous
//
#include <hip/hip_runtime.h>

#define B_    1024
#define N_    100000
#define NP_   100096   // N padded to multiple of 64 (n-tile)
#define NR_   500
#define D_    200
#define KP_   224      // D padded to multiple of 32 (MFMA K)
#define OC_   32
#define FW_   9
#define L_    192
#define OCL_  6144     // OC_*L_
#define KSPLIT_ 8
#define EPS_  1e-5f

typedef __attribute__((ext_vector_type(8))) short  bf16x8;
typedef __attribute__((ext_vector_type(4))) float  f32x4;

static __device__ __forceinline__ unsigned short f2bf(float x) {
    unsigned int u = __float_as_uint(x);
    unsigned int r = (u + 0x7FFFu + ((u >> 16) & 1u)) >> 16;
    return (unsigned short)r;
}

// ---------------- Stage A: x = bn0(E[e1]), k = bn1-scale * (R[r]@W_fc1 + b_fc1),
// y[b,o,l] = sum_w x[l+w]*k[o,w] + t1[o]  -> y_ws[b][o*L+l] ----------------
__global__ __launch_bounds__(256) void kA(
    const int* __restrict__ e1_idx, const int* __restrict__ r_idx,
    const float* __restrict__ E, const float* __restrict__ R,
    const float* __restrict__ W_fc1, const float* __restrict__ b_fc1,
    const float* __restrict__ bn0_g, const float* __restrict__ bn0_b,
    const float* __restrict__ bn0_m, const float* __restrict__ bn0_v,
    const float* __restrict__ bn1_g, const float* __restrict__ bn1_b,
    const float* __restrict__ bn1_m, const float* __restrict__ bn1_v,
    float* __restrict__ y_ws)
{
    __shared__ float x_lds[D_];
    __shared__ float r_lds[D_];
    __shared__ float k_lds[OC_ * FW_];
    __shared__ float s1_lds[OC_], t1_lds[OC_];

    const int b   = blockIdx.x;
    const int tid = threadIdx.x;

    const float s0 = bn0_g[0] / sqrtf(bn0_v[0] + EPS_);
    const float c0 = bn0_b[0] - bn0_m[0] * s0;

    if (tid < D_) {
        x_lds[tid] = E[(long)e1_idx[b] * D_ + tid] * s0 + c0;
        r_lds[tid] = R[(long)r_idx[b] * D_ + tid];
    } else if (tid >= 224) {
        int o = tid - 224;
        float s1 = bn1_g[o] / sqrtf(bn1_v[o] + EPS_);
        s1_lds[o] = s1;
        t1_lds[o] = bn1_b[o] - bn1_m[o] * s1;
    }
    __syncthreads();

    for (int j = tid; j < OC_ * FW_; j += 256) {
        float acc = b_fc1[j];
        #pragma unroll 4
        for (int d = 0; d < D_; ++d)
            acc += r_lds[d] * W_fc1[d * (OC_ * FW_) + j];
        k_lds[j] = acc * s1_lds[j / FW_];
    }
    __syncthreads();

    float* yrow = y_ws + (long)b * OCL_;
    for (int idx = tid; idx < OCL_; idx += 256) {
        int o = idx / L_;
        int l = idx - o * L_;
        const float* kp = &k_lds[o * FW_];
        float acc = t1_lds[o];
        #pragma unroll
        for (int w = 0; w < FW_; ++w)
            acc += x_lds[l + w] * kp[w];
        yrow[idx] = acc;
    }
}

// ---------------- Stage B: pre[ks][b][d] = partial( y[b,:] @ W_fc[:,d] ) ----------------
// grid: (d_tiles=4, b_tiles=16, ksplit=8); tile 64b x 64d; micro 4x4
__global__ __launch_bounds__(256) void kB(
    const float* __restrict__ y_ws, const float* __restrict__ W_fc,
    float* __restrict__ pre)
{
    __shared__ float y_lds[64][68];   // [k][b]
    __shared__ float w_lds[64][68];   // [k][d]

    const int tid = threadIdx.x;
    const int d0 = blockIdx.x * 64;
    const int b0 = blockIdx.y * 64;
    const int k0 = blockIdx.z * (OCL_ / KSPLIT_);
    const int tx = tid & 15, ty = tid >> 4;

    float acc[4][4] = {};

    for (int kc = 0; kc < OCL_ / KSPLIT_; kc += 64) {
        #pragma unroll
        for (int i = 0; i < 16; ++i) {
            int t = tid + i * 256;
            int hi = t >> 6, lo = t & 63;
            y_lds[lo][hi] = y_ws[(long)(b0 + hi) * OCL_ + (k0 + kc + lo)];
            w_lds[hi][lo] = (d0 + lo < D_)
                ? W_fc[(long)(k0 + kc + hi) * D_ + (d0 + lo)] : 0.f;
        }
        __syncthreads();
        #pragma unroll
        for (int kk = 0; kk < 64; ++kk) {
            float4 yv = *(const float4*)&y_lds[kk][ty * 4];
            float4 wv = *(const float4*)&w_lds[kk][tx * 4];
            float ya[4] = {yv.x, yv.y, yv.z, yv.w};
            float wa[4] = {wv.x, wv.y, wv.z, wv.w};
            #pragma unroll
            for (int i = 0; i < 4; ++i)
                #pragma unroll
                for (int j = 0; j < 4; ++j)
                    acc[i][j] += ya[i] * wa[j];
        }
        __syncthreads();
    }

    #pragma unroll
    for (int i = 0; i < 4; ++i) {
        int brow = b0 + ty * 4 + i;
        #pragma unroll
        for (int j = 0; j < 4; ++j) {
            int d = d0 + tx * 4 + j;
            if (d < D_)
                pre[((long)blockIdx.z * B_ + brow) * D_ + d] = acc[i][j];
        }
    }
}

// ---------------- Stage B2: reduce splits + bias + bn2 + relu -> h_bf (bf16, K-padded) ----
__global__ __launch_bounds__(256) void kB2(
    const float* __restrict__ pre, const float* __restrict__ b_fc,
    const float* __restrict__ bn2_g, const float* __restrict__ bn2_b,
    const float* __restrict__ bn2_m, const float* __restrict__ bn2_v,
    unsigned short* __restrict__ h_bf)
{
    int id = blockIdx.x * 256 + threadIdx.x;
    if (id >= B_ * KP_) return;
    int b = id / KP_;
    int d = id - b * KP_;
    float h = 0.f;
    if (d < D_) {
        float s = 0.f;
        #pragma unroll
        for (int sp = 0; sp < KSPLIT_; ++sp)
            s += pre[(long)sp * B_ * D_ + b * D_ + d];
        float s2 = bn2_g[d] / sqrtf(bn2_v[d] + EPS_);
        h = (s + b_fc[d] - bn2_m[d]) * s2 + bn2_b[d];
        h = fmaxf(h, 0.f);
    }
    h_bf[id] = f2bf(h);
}

// ---------------- Stage E-convert: E fp32 [N][200] -> E_bf [NP][224] bf16 (zero-padded) ---
__global__ __launch_bounds__(256) void kE(
    const float* __restrict__ E, unsigned short* __restrict__ E_bf)
{
    long id = (long)blockIdx.x * 256 + threadIdx.x;   // unit: 4 bf16
    if (id >= (long)NP_ * (KP_ / 4)) return;
    int n = (int)(id / (KP_ / 4));
    int c = (int)(id - (long)n * (KP_ / 4));
    ushort4 o = {0, 0, 0, 0};
    if (n < N_ && c < D_ / 4) {
        float4 v = *(const float4*)&E[(long)n * D_ + c * 4];
        o.x = f2bf(v.x); o.y = f2bf(v.y); o.z = f2bf(v.z); o.w = f2bf(v.w);
    }
    *(ushort4*)&E_bf[(long)n * KP_ + c * 4] = o;
}

// ---------------- Stage C: out[b][n] = sigmoid(h[b,:] . E[n,:] + bias[n]) ---------------
// MFMA 16x16x32 bf16. Wave tile 32m x 64n, block = 4 waves stacked on m (128m x 64n).
// grid (8 m-tiles, 1563 n-tiles), m fastest so co-scheduled blocks share E tile in L2.
// A-frag: row = m0+ (lane&15), k = quad*8+j (contig 16B). B-frag: row n, same k slice.
// C/D: col(n) = lane&15, row(m) = quad*4 + reg.
__global__ __launch_bounds__(256) void kC(
    const unsigned short* __restrict__ h_bf, const unsigned short* __restrict__ E_bf,
    const float* __restrict__ bias, float* __restrict__ out)
{
    const int wave = threadIdx.x >> 6;
    const int lane = threadIdx.x & 63;
    const int quad = lane >> 4;
    const int lc   = lane & 15;

    const int m0 = blockIdx.x * 128 + wave * 32;   // wave covers m0..m0+31
    const int n0 = blockIdx.y * 64;

    f32x4 acc[2][4] = {};

    const short* hbase0 = (const short*)h_bf + (long)(m0 + lc) * KP_ + quad * 8;
    const short* hbase1 = hbase0 + 16 * KP_;

    #pragma unroll
    for (int k0 = 0; k0 < KP_; k0 += 32) {
        bf16x8 a0 = *(const bf16x8*)(hbase0 + k0);
        bf16x8 a1 = *(const bf16x8*)(hbase1 + k0);
        #pragma unroll
        for (int t = 0; t < 4; ++t) {
            int n = n0 + t * 16 + lc;
            bf16x8 b = *(const bf16x8*)((const short*)E_bf + (long)n * KP_ + k0 + quad * 8);
            acc[0][t] = __builtin_amdgcn_mfma_f32_16x16x32_bf16(a0, b, acc[0][t], 0, 0, 0);
            acc[1][t] = __builtin_amdgcn_mfma_f32_16x16x32_bf16(a1, b, acc[1][t], 0, 0, 0);
        }
    }

    #pragma unroll
    for (int t = 0; t < 4; ++t) {
        int n = n0 + t * 16 + lc;
        if (n < N_) {
            float bv = bias[n];
            #pragma unroll
            for (int mi = 0; mi < 2; ++mi) {
                #pragma unroll
                for (int r = 0; r < 4; ++r) {
                    int m = m0 + mi * 16 + quad * 4 + r;
                    float v = acc[mi][t][r] + bv;
                    out[(long)m * N_ + n] = 1.f / (1.f + __expf(-v));
                }
            }
        }
    }
}

extern "C" void kernel_launch(void* const* d_in, const int* in_sizes, int n_in,
                              void* d_out, int out_size, void* d_ws, size_t ws_size,
                              hipStream_t stream) {
    const int*   e1_idx = (const int*)d_in[0];
    const int*   r_idx  = (const int*)d_in[1];
    const float* E      = (const float*)d_in[2];
    const float* R      = (const float*)d_in[3];
    const float* W_fc   = (const float*)d_in[4];
    const float* b_fc   = (const float*)d_in[5];
    const float* W_fc1  = (const float*)d_in[6];
    const float* b_fc1  = (const float*)d_in[7];
    const float* bn0_g  = (const float*)d_in[8];
    const float* bn0_b  = (const float*)d_in[9];
    const float* bn0_m  = (const float*)d_in[10];
    const float* bn0_v  = (const float*)d_in[11];
    const float* bn1_g  = (const float*)d_in[12];
    const float* bn1_b  = (const float*)d_in[13];
    const float* bn1_m  = (const float*)d_in[14];
    const float* bn1_v  = (const float*)d_in[15];
    const float* bn2_g  = (const float*)d_in[16];
    const float* bn2_b  = (const float*)d_in[17];
    const float* bn2_m  = (const float*)d_in[18];
    const float* bn2_v  = (const float*)d_in[19];
    const float* bias   = (const float*)d_in[20];
    float* out = (float*)d_out;

    // ws layout:
    //   region0 [0, NP_*KP_*2) = 44,843,008 B:
    //     phase 1 (kA/kB/kB2): y_ws (B*OCL*4 = 25,165,824 B) then pre (8*B*D*4 = 6,553,600 B)
    //     phase 2 (kE/kC):     E_bf bf16 [NP_][KP_]  (overwrites y_ws/pre after they're dead)
    //   region1: h_bf bf16 [B_][KP_] = 458,752 B
    char* base = (char*)d_ws;
    unsigned short* E_bf = (unsigned short*)base;
    float* y_ws = (float*)base;
    float* pre  = y_ws + (long)B_ * OCL_;
    unsigned short* h_bf = (unsigned short*)(base + (long)NP_ * KP_ * 2);

    kA<<<B_, 256, 0, stream>>>(e1_idx, r_idx, E, R, W_fc1, b_fc1,
                               bn0_g, bn0_b, bn0_m, bn0_v,
                               bn1_g, bn1_b, bn1_m, bn1_v, y_ws);
    kB<<<dim3(4, 16, KSPLIT_), 256, 0, stream>>>(y_ws, W_fc, pre);
    kB2<<<(B_ * KP_ + 255) / 256, 256, 0, stream>>>(pre, b_fc, bn2_g, bn2_b, bn2_m, bn2_v, h_bf);
    kE<<<(int)(((long)NP_ * (KP_ / 4) + 255) / 256), 256, 0, stream>>>(E, E_bf);
    kC<<<dim3(8, NP_ / 64), 256, 0, stream>>>(h_bf, E_bf, bias, out);
}